// Round 18
// baseline (43.468 us; speedup 1.0000x reference)
//
#include <hip/hip_runtime.h>
#include <math.h>

#define N_ATOMS 4096
#define NTILE   16               // i-tiles of 256
#define NJ      64               // j slices
#define JT      64               // j atoms per slice
#define LOG2E   1.4426950408889634f
#define LN2     0.6931471805599453f

typedef float v2f __attribute__((ext_vector_type(2)));
typedef unsigned long long u64;

__device__ __forceinline__ float pow20f(float t) {
    float t2 = t * t, t4 = t2 * t2, t8 = t4 * t4, t16 = t8 * t8;
    return t16 * t4;
}

// deterministic block reduction (256 threads); result broadcast via red[0..3]
__device__ __forceinline__ float block_reduce(float v, float* red) {
    __syncthreads();
    #pragma unroll
    for (int off = 32; off > 0; off >>= 1) v += __shfl_down(v, off, 64);
    if ((threadIdx.x & 63) == 0) red[threadIdx.x >> 6] = v;
    __syncthreads();
    return (red[0] + red[1]) + (red[2] + red[3]);
}

// K0: zero the 17 completion counters (1 tiny block; graph replay re-runs it,
// so every call starts from 0 and "last" tests are exact).
__global__ __launch_bounds__(32) void zero_ctrs(unsigned int* __restrict__ ctrs)
{
    if (threadIdx.x < NTILE + 1) ctrs[threadIdx.x] = 0u;
}

// Single fused main kernel. grid (16,64) x 256. Thread owns i = bi*256+tid.
//  - in-block pack of slice constants (+certified rc2 via bisection)
//  - phase1: r^2 vs rc2 over 32 j-pairs (packed v2f) -> 64-bit hit mask
//  - phase2a: ctz over hits, f_r eval (~2% of pairs), sets phi bits
//  - phase2b: ctz over phi bits (j>i), full phi eval
//  - tail: tile-last block (release/acquire counter) embeds its tile's 256
//    atoms; global-last block does the fixed-order final sum.
__global__ __launch_bounds__(256) void eam_fused(
    const float* __restrict__ coords, const float* __restrict__ params,
    float* __restrict__ rho_part,    // [NJ][N_ATOMS]
    float* __restrict__ e_part,      // [NTILE*NJ]
    float* __restrict__ tile_sum,    // [NTILE]
    unsigned int* __restrict__ tctr, // [NTILE], zeroed by K0
    unsigned int* __restrict__ gctr, // [1],     zeroed by K0
    float* __restrict__ out)
{
    __shared__ float4 srho4[JT];         // 32 pairs x 2 float4 = 1 KB
    __shared__ float4 sphi4[JT * 3];     // 3 KB
    __shared__ float red[4];
    __shared__ int sTileLast, sGlobLast;

    const int tid = threadIdx.x;
    const int bi  = blockIdx.x;      // 0..15
    const int s   = blockIdx.y;      // 0..63
    const int i   = bi * 256 + tid;
    const int jbase = s * JT;

    if (tid < JT) {   // pack slice atom jbase+tid into LDS, incl. certified rc2
        const int j = jbase + tid;
        const float* p = params + 22 * j;
        const float x = coords[3*j], y = coords[3*j+1], z = coords[3*j+2];
        const float re = p[0], fe = p[1], be = p[5], al = p[4], la = p[9];
        const float rei  = __builtin_amdgcn_rcpf(re);
        const float bl2  = be * LOG2E;
        const float al2  = al * LOG2E;
        const float l2fe = __builtin_amdgcn_logf(fe);   // log2

        // bisection: g(x) = l2fe - bl2*(x-1) - log2(1+(x-la)^20) + 19.93  (f = 1e-6)
        float lo = la + 1.0f, hi = la + 6.0f;
        #pragma unroll 1
        for (int it = 0; it < 28; ++it) {
            const float mid = 0.5f * (lo + hi);
            const float g   = l2fe - bl2 * (mid - 1.0f)
                            - __builtin_amdgcn_logf(1.0f + pow20f(mid - la)) + 19.93f;
            if (g > 0.0f) lo = mid; else hi = mid;
        }
        const float rc  = re * hi;                 // conservative side
        const float rc2 = fmaxf(rc * rc, 25.01f);  // phi-set (r<=5) always included

        sphi4[tid * 3 + 0] = { x, y, z, rei };
        sphi4[tid * 3 + 1] = { -bl2 * rei, bl2 + l2fe, -la, p[7] * __builtin_amdgcn_rcpf(fe) };
        sphi4[tid * 3 + 2] = { -al2 * rei, al2, -p[8], p[6] };
        float* rd = (float*)srho4 + 8 * (tid >> 1) + (tid & 1);
        rd[0] = x; rd[2] = y; rd[4] = z; rd[6] = rc2;
    }

    // i-side constants (per-thread, straight from params; L1/L2-resident)
    const float* pi = params + 22 * i;
    const float xi = coords[3*i], yi = coords[3*i+1], zi = coords[3*i+2];
    const float rei_i  = __builtin_amdgcn_rcpf(pi[0]);
    const float bl2_i  = pi[5] * LOG2E;
    const float al2_i  = pi[4] * LOG2E;
    const float c0b_i  = -bl2_i * rei_i;
    const float c1bp_i = bl2_i + __builtin_amdgcn_logf(pi[1]);
    const float c0a_i  = -al2_i * rei_i;
    const float mla_i  = -pi[9];
    const float mka_i  = -pi[8];
    const float A_i    = pi[6];
    const float Bof_i  = pi[7] * __builtin_amdgcn_rcpf(pi[1]);

    __syncthreads();

    const v2f xi2 = { xi, xi }, yi2 = { yi, yi }, zi2 = { zi, zi };
    u64 hits = 0ull;

    #pragma unroll 4
    for (int k = 0; k < JT / 2; ++k) {
        const float4 f0 = srho4[k * 2 + 0];   // x0,x1,y0,y1
        const float4 f1 = srho4[k * 2 + 1];   // z0,z1,rc2_0,rc2_1
        const v2f x01 = { f0.x, f0.y }, y01 = { f0.z, f0.w };
        const v2f z01 = { f1.x, f1.y };
        const v2f dx = x01 - xi2, dy = y01 - yi2, dz = z01 - zi2;
        const v2f r2v = dx * dx + dy * dy + dz * dz;
        if (r2v.x <= f1.z) hits |= (1ull << (2 * k));
        if (r2v.y <= f1.w) hits |= (1ull << (2 * k + 1));
    }

    const int t = i - jbase;   // slice-local index of i (may be out of range)
    float rho = 0.0f;
    u64 phim = 0ull;

    {   // phase2a: f_r for hit pairs
        u64 m = hits;
        if (t >= 0 && t < JT) m &= ~(1ull << t);   // skip self (r=0)
        while (m) {
            const int k = __builtin_ctzll(m);
            m &= m - 1;
            const float4 q0 = sphi4[k * 3 + 0];   // x,y,z,rei
            const float4 q1 = sphi4[k * 3 + 1];   // c0b,c1bp,mla,Bof
            const float dx = q0.x - xi, dy = q0.y - yi, dz = q0.z - zi;
            const float r2 = fmaf(dx, dx, fmaf(dy, dy, dz * dz));
            const float r  = __builtin_amdgcn_sqrtf(r2);
            const float fr = __builtin_amdgcn_exp2f(fmaf(r, q1.x, q1.y))
                           * __builtin_amdgcn_rcpf(1.0f + pow20f(fmaf(r, q0.w, q1.z)));
            rho += fr;
            if (r2 <= 25.0f && k > t) phim |= (1ull << k);
        }
    }
    rho_part[(size_t)s * N_ATOMS + i] = rho;

    float e = 0.0f;
    while (phim) {   // phase2b: phi for pairs within 5 A, j > i
        const int k = __builtin_ctzll(phim);
        phim &= phim - 1;
        const float4 q0 = sphi4[k * 3 + 0];
        const float4 q1 = sphi4[k * 3 + 1];
        const float4 q2 = sphi4[k * 3 + 2];
        const float dx = q0.x - xi, dy = q0.y - yi, dz = q0.z - zi;
        const float r = __builtin_amdgcn_sqrtf(fmaf(dx, dx, fmaf(dy, dy, dz * dz)));

        const float fri = __builtin_amdgcn_exp2f(fmaf(r, c0b_i, c1bp_i))
                        * __builtin_amdgcn_rcpf(1.0f + pow20f(fmaf(r, rei_i, mla_i)));
        const float frj = __builtin_amdgcn_exp2f(fmaf(r, q1.x, q1.y))
                        * __builtin_amdgcn_rcpf(1.0f + pow20f(fmaf(r, q0.w, q1.z)));
        const float ph_i = A_i * __builtin_amdgcn_exp2f(fmaf(r, c0a_i, al2_i))
                               * __builtin_amdgcn_rcpf(1.0f + pow20f(fmaf(r, rei_i, mka_i)))
                         - Bof_i * fri;
        const float ph_j = q2.w * __builtin_amdgcn_exp2f(fmaf(r, q2.x, q2.y))
                                * __builtin_amdgcn_rcpf(1.0f + pow20f(fmaf(r, q0.w, q2.z)))
                         - q1.w * frj;
        // frj/fri*ph_i + fri/frj*ph_j = (frj^2*ph_i + fri^2*ph_j)/(fri*frj)
        e += 0.5f * fmaf(frj * frj, ph_i, fri * fri * ph_j)
                  * __builtin_amdgcn_rcpf(fri * frj);
    }

    const float eb = block_reduce(e, red);
    if (tid == 0) {
        e_part[bi * NJ + s] = eb;
        // release: rho slice + e partial visible device-wide before the count
        unsigned int prev = __hip_atomic_fetch_add(&tctr[bi], 1u, __ATOMIC_ACQ_REL,
                                                   __HIP_MEMORY_SCOPE_AGENT);
        sTileLast = (prev == (unsigned)(NJ - 1));
    }
    __syncthreads();
    if (!sTileLast) return;

    // ---- tile-last block: embed tile bi's 256 atoms (acquire above) ----
    float rsum0 = 0.0f, rsum1 = 0.0f, rsum2 = 0.0f, rsum3 = 0.0f;
    #pragma unroll 4
    for (int ss = 0; ss < NJ; ss += 4) {   // coalesced per ss
        rsum0 += rho_part[(size_t)(ss + 0) * N_ATOMS + i];
        rsum1 += rho_part[(size_t)(ss + 1) * N_ATOMS + i];
        rsum2 += rho_part[(size_t)(ss + 2) * N_ATOMS + i];
        rsum3 += rho_part[(size_t)(ss + 3) * N_ATOMS + i];
    }
    const float rhoi = (rsum0 + rsum1) + (rsum2 + rsum3);

    float F;
    {
        const float* p = params + 22 * i;
        if (rhoi < p[20]) {
            const float xn = rhoi / p[20] - 1.0f;
            F = p[10] + xn * (p[11] + xn * (p[12] + xn * p[13]));
        } else if (rhoi < p[21]) {
            const float xe = rhoi / p[2] - 1.0f;
            F = p[14] + xe * (p[15] + xe * (p[16] + xe * p[17]));
        } else {
            const float l2 = __builtin_amdgcn_logf(rhoi / p[3]);   // log2
            const float tt = __builtin_amdgcn_exp2f(p[18] * l2);
            const float lt = p[18] * l2 * LN2;                     // ln
            F = p[19] * (1.0f - lt) * tt;
        }
    }

    float v = F + ((tid < NJ) ? e_part[bi * NJ + tid] : 0.0f);
    const float tot = block_reduce(v, red);
    if (tid == 0) {
        tile_sum[bi] = tot;
        unsigned int prev = __hip_atomic_fetch_add(gctr, 1u, __ATOMIC_ACQ_REL,
                                                   __HIP_MEMORY_SCOPE_AGENT);
        sGlobLast = (prev == (unsigned)(NTILE - 1));
    }
    __syncthreads();

    if (sGlobLast && tid == 0) {   // global-last: fixed-order final sum
        float total = 0.0f;
        #pragma unroll
        for (int w = 0; w < NTILE; ++w) total += tile_sum[w];
        out[0] = total;
    }
}

extern "C" void kernel_launch(void* const* d_in, const int* in_sizes, int n_in,
                              void* d_out, int out_size, void* d_ws, size_t ws_size,
                              hipStream_t stream) {
    const float* coords = (const float*)d_in[0];   // [4096][3]
    const float* params = (const float*)d_in[1];   // [4096][22]
    float* out = (float*)d_out;

    float* rho_part = (float*)d_ws;                          // [64][4096]
    float* e_part   = rho_part + (size_t)NJ * N_ATOMS;       // [1024]
    float* tile_sum = e_part + NTILE * NJ;                   // [16]
    unsigned int* tctr = (unsigned int*)(tile_sum + NTILE);  // [16]
    unsigned int* gctr = tctr + NTILE;                       // [1]

    zero_ctrs<<<1, 32, 0, stream>>>(tctr);   // zeroes tctr[0..15] and gctr
    dim3 grid(NTILE, NJ);
    eam_fused<<<grid, 256, 0, stream>>>(coords, params, rho_part, e_part,
                                        tile_sum, tctr, gctr, out);
}